// Round 2
// baseline (312.457 us; speedup 1.0000x reference)
//
#include <hip/hip_runtime.h>

#define E_DIM  256
#define N_E    16384
#define N_ROWS 8192
#define HW     1024
#define NPART  64           // n-tiles of 256 cols

typedef _Float16 f16x8 __attribute__((ext_vector_type(8)));
typedef float    f32x4 __attribute__((ext_vector_type(4)));

#define ESCALE   1048576.0f          // 2^20 (exact)
#define UNSCALE  1.9073486328125e-6f // 2^-19: acc*2^-19 == 2*dot

// async 16B global->LDS copy: HW writes lds_base + lane*16 (wave-uniform base)
__device__ __forceinline__ void gld_lds16(_Float16* lds, const _Float16* g) {
  __builtin_amdgcn_global_load_lds(
      (__attribute__((address_space(1))) void*)(g),
      (__attribute__((address_space(3))) void*)(lds), 16, 0, 0);
}

// ---------- fused prep (verbatim R11, passed) ----------
#define ZB_Z    256
#define EB_E    512
__global__ __launch_bounds__(256) void k_prep(const float* __restrict__ z,
                                              const float* __restrict__ E,
                                              _Float16* __restrict__ Ah,
                                              _Float16* __restrict__ Al,
                                              _Float16* __restrict__ Bh,
                                              _Float16* __restrict__ Bl,
                                              float* __restrict__ eNorm,
                                              float* __restrict__ zNorm,
                                              float* __restrict__ out_loss) {
#pragma clang fp contract(off)
  const int bi = blockIdx.x, t = threadIdx.x;

  if (bi < ZB_Z) {
    // ---- z section: 32-row tile ----
    __shared__ float sLZ[256][32];   // 32 KB z tile [channel][row]
    __shared__ float sN2[16][32];    // chain partials [c16][row]
    const int n0 = bi * 32;
    const int b = n0 >> 10, hw0 = n0 & 1023;

    {
      const int nl = t & 31, cs = t >> 5;
      const float* zb = z + (size_t)b * E_DIM * HW + hw0 + nl;
#pragma unroll 4
      for (int it = 0; it < 32; ++it) {
        int c = it * 8 + cs;
        sLZ[c][nl] = zb[(size_t)c * HW];
      }
    }
    __syncthreads();

    // phase L: limbs. thread = (row nl, segment seg = kc)
    {
      const int nl = t & 31, seg = t >> 5;
      const int n = n0 + nl;
      const int perm = (n >> 1) & 3;
#pragma unroll
      for (int u = 0; u < 4; ++u) {
        const int c0 = seg * 32 + u * 8;
        f16x8 hh, ll;
#pragma unroll
        for (int j = 0; j < 8; ++j) {
          float v = sLZ[c0 + j][nl];
          _Float16 hi = (_Float16)v;
          hh[j] = hi;
          ll[j] = (_Float16)(v - (float)hi);
        }
        size_t dst = (size_t)seg * (N_ROWS * 32) + (size_t)n * 32 + (size_t)(u ^ perm) * 8;
        *(f16x8*)&Ah[dst] = hh;
        *(f16x8*)&Al[dst] = ll;
      }
    }

    // phase N: numpy-exact chains
#pragma unroll
    for (int it = 0; it < 2; ++it) {
      int task = it * 256 + t;
      int nl = task & 31, c16 = task >> 5;
      int h = c16 >> 3, j = c16 & 7;
      float r = 0.f;
#pragma unroll
      for (int i = 0; i < 16; ++i) {
        float v = sLZ[h * 128 + i * 8 + j][nl];
        r = r + v * v;
      }
      sN2[c16][nl] = r;
    }
    __syncthreads();
    if (t < 32) {
      float q[16];
#pragma unroll
      for (int c16 = 0; c16 < 16; ++c16) q[c16] = sN2[c16][t];
      float h0 = ((q[0] + q[1]) + (q[2] + q[3])) + ((q[4] + q[5]) + (q[6] + q[7]));
      float h1 = ((q[8] + q[9]) + (q[10] + q[11])) + ((q[12] + q[13]) + (q[14] + q[15]));
      zNorm[n0 + t] = h0 + h1;
    }
  } else {
    // ---- E section ----
    __shared__ float sNP[8][32];
    const int be = bi - ZB_Z;
    if (be == 0 && t == 0) out_loss[0] = 0.f;
    const int kc = t >> 5, rl = t & 31;
    const int k = be * 32 + rl;
    const int perm = (k >> 1) & 3;
    const float* src = E + (size_t)k * E_DIM + kc * 32;

    float4 v4[8];
#pragma unroll
    for (int u2 = 0; u2 < 8; ++u2) v4[u2] = ((const float4*)src)[u2];

    float nsum = 0.f;
    size_t base = (size_t)kc * (N_E * 32) + (size_t)k * 32;
#pragma unroll
    for (int u = 0; u < 4; ++u) {
      float v[8] = {v4[u * 2].x, v4[u * 2].y, v4[u * 2].z, v4[u * 2].w,
                    v4[u * 2 + 1].x, v4[u * 2 + 1].y, v4[u * 2 + 1].z, v4[u * 2 + 1].w};
      f16x8 hh, ll;
#pragma unroll
      for (int j = 0; j < 8; ++j) {
        nsum = nsum + v[j] * v[j];
        float s = v[j] * ESCALE;
        _Float16 hi = (_Float16)s;
        hh[j] = hi;
        ll[j] = (_Float16)(s - (float)hi);
      }
      *(f16x8*)&Bh[base + (size_t)(u ^ perm) * 8] = hh;
      *(f16x8*)&Bl[base + (size_t)(u ^ perm) * 8] = ll;
    }
    sNP[kc][rl] = nsum;
    __syncthreads();
    if (t < 32) {
      float s = 0.f;
#pragma unroll
      for (int kc2 = 0; kc2 < 8; ++kc2) s += sNP[kc2][t];
      eNorm[be * 32 + t] = s;
    }
  }
}

// ---------- main: fp16-limb MFMA GEMM. R14: 256x256 dbuf kept; schedule fixed.
// Per kc: {issue ALL 8 gld_lds prefetches (pinned early, full-kc vmcnt cover) |
// ds_read A+B-lo | setprio(1) 48 MFMA | ds_read B-hi | setprio(1) 48 MFMA |
// __syncthreads (vmcnt drain now free)}. NO intra-kc barriers, NO forced
// lgkmcnt(0): compiler emits counted lgkmcnt and overlaps drain with MFMA;
// waves drift within the kc (m114 overlap) and resync once per kc.
__global__ __launch_bounds__(512, 2) void k_scores_mfma(
    const _Float16* __restrict__ Ah, const _Float16* __restrict__ Al,
    const _Float16* __restrict__ Bh, const _Float16* __restrict__ Bl,
    const float* __restrict__ eNorm, const float* __restrict__ zNorm,
    float* __restrict__ pVal, int* __restrict__ pIdx) {
#pragma clang fp contract(off)
  __shared__ alignas(16) _Float16 L[2][2][2][256][32];  // 128 KiB

  const int mt = blockIdx.x, nt = blockIdx.y;
  const int m0 = mt * 256, n0 = nt * 256;

  const int t = threadIdx.x;
  const int lane = t & 63, w = t >> 6;
  const int tx = lane & 15, quad = lane >> 4;
  const int wr = w & 3, wc = w >> 2;          // wave grid 4 (m) x 2 (n)
  const int wm = wr * 64, wn = wc * 128;      // per-wave output 64 x 128
  const int swz = (quad ^ ((tx >> 1) & 3)) * 8;  // physical f16 offset of logical block

  // staging role: wave w stages array (w>>1 in {Ah,Al,Bh,Bl}), half (w&1)
  const int arr = w >> 1, hf = w & 1;
  const _Float16* gstage;
  size_t plane;
  _Float16* lstage0;
  if (arr == 0)      { gstage = Ah + (size_t)(m0 + hf * 128) * 32; plane = (size_t)N_ROWS * 32; lstage0 = &L[0][0][0][hf * 128][0]; }
  else if (arr == 1) { gstage = Al + (size_t)(m0 + hf * 128) * 32; plane = (size_t)N_ROWS * 32; lstage0 = &L[0][0][1][hf * 128][0]; }
  else if (arr == 2) { gstage = Bh + (size_t)(n0 + hf * 128) * 32; plane = (size_t)N_E * 32;    lstage0 = &L[0][1][0][hf * 128][0]; }
  else               { gstage = Bl + (size_t)(n0 + hf * 128) * 32; plane = (size_t)N_E * 32;    lstage0 = &L[0][1][1][hf * 128][0]; }
  gstage += lane * 8;

  f32x4 acc[4][8];
#pragma unroll
  for (int i = 0; i < 4; ++i)
#pragma unroll
    for (int j = 0; j < 8; ++j) acc[i][j] = (f32x4){0.f, 0.f, 0.f, 0.f};

  // prologue: stage kc=0 into buf 0 (8 x 1KB per wave), drain, fence
  {
#pragma unroll
    for (int c = 0; c < 8; ++c) gld_lds16(lstage0 + c * 512, gstage + c * 512);
  }
  __syncthreads();   // vmcnt(0)+lgkmcnt(0) drain + barrier + fence

#pragma unroll 2
  for (int kc = 0; kc < 8; ++kc) {
    const int buf = kc & 1;
    const _Float16* Ab = &L[buf][0][0][0][0];
    const _Float16* Bb = &L[buf][1][0][0][0];

    // ---- prefetch kc+1: all 8 loads up front -> full-kc issue-to-drain cover
    if (kc < 7) {
      _Float16* lpre = lstage0 + (size_t)(buf ^ 1) * 32768;   // other buffer
      const _Float16* gpre = gstage + (size_t)(kc + 1) * plane;
#pragma unroll
      for (int c = 0; c < 8; ++c) gld_lds16(lpre + c * 512, gpre + c * 512);
      __builtin_amdgcn_sched_barrier(0);   // pin prefetch issue before compute
    }

    f16x8 ah[4], al[4], bh[4], bl[4];

    // ---------- half 0: A-frags + B cols [wn, wn+64) ----------
#pragma unroll
    for (int i = 0; i < 4; ++i) {
      const int ro = (wm + i * 16 + tx) * 32 + swz;
      ah[i] = *(const f16x8*)&Ab[ro];
      al[i] = *(const f16x8*)&Ab[ro + 8192];
    }
#pragma unroll
    for (int j = 0; j < 4; ++j) {
      const int ro = (wn + j * 16 + tx) * 32 + swz;
      bh[j] = *(const f16x8*)&Bb[ro];
      bl[j] = *(const f16x8*)&Bb[ro + 8192];
    }
    __builtin_amdgcn_s_setprio(1);
#pragma unroll
    for (int i = 0; i < 4; ++i)
#pragma unroll
      for (int j = 0; j < 4; ++j) {
        acc[i][j] = __builtin_amdgcn_mfma_f32_16x16x32_f16(ah[i], bh[j], acc[i][j], 0, 0, 0);
        acc[i][j] = __builtin_amdgcn_mfma_f32_16x16x32_f16(ah[i], bl[j], acc[i][j], 0, 0, 0);
        acc[i][j] = __builtin_amdgcn_mfma_f32_16x16x32_f16(al[i], bh[j], acc[i][j], 0, 0, 0);
      }
    __builtin_amdgcn_s_setprio(0);

    // ---------- half 1: B cols [wn+64, wn+128), A held in regs ----------
#pragma unroll
    for (int j = 0; j < 4; ++j) {
      const int ro = (wn + 64 + j * 16 + tx) * 32 + swz;
      bh[j] = *(const f16x8*)&Bb[ro];
      bl[j] = *(const f16x8*)&Bb[ro + 8192];
    }
    __builtin_amdgcn_s_setprio(1);
#pragma unroll
    for (int i = 0; i < 4; ++i)
#pragma unroll
      for (int j = 0; j < 4; ++j) {
        acc[i][4 + j] = __builtin_amdgcn_mfma_f32_16x16x32_f16(ah[i], bh[j], acc[i][4 + j], 0, 0, 0);
        acc[i][4 + j] = __builtin_amdgcn_mfma_f32_16x16x32_f16(ah[i], bl[j], acc[i][4 + j], 0, 0, 0);
        acc[i][4 + j] = __builtin_amdgcn_mfma_f32_16x16x32_f16(al[i], bh[j], acc[i][4 + j], 0, 0, 0);
      }
    __builtin_amdgcn_s_setprio(0);

    __syncthreads();   // kc boundary: vmcnt(0) drain (prefetch fully covered) + fence
  }

  // ---- epilogue: score + argmin (first-index tie-break) ----
  float* sF  = (float*)&L[0][0][0][0][0];
  float* zNl = sF;                  // [256]
  float* eNl = sF + 256;            // [256]
  float* sV  = sF + 512;            // [2][256]
  int*   sI  = (int*)(sF + 1024);   // [2][256]
  if (t < 256) zNl[t] = zNorm[m0 + t];
  else         eNl[t - 256] = eNorm[n0 + t - 256];
  __syncthreads();

#pragma unroll
  for (int i = 0; i < 4; ++i) {
#pragma unroll
    for (int r = 0; r < 4; ++r) {
      const int rloc = wm + i * 16 + quad * 4 + r;
      const float zn = zNl[rloc];
      float bv = 3.4e38f;
      int bc = 0x7fffffff;
#pragma unroll
      for (int jj = 0; jj < 8; ++jj) {
        const int col = wn + jj * 16 + tx;
        float s = (zn + eNl[col]) - acc[i][jj][r] * UNSCALE;
        if (s < bv) { bv = s; bc = n0 + col; }   // jj ascending: strict < keeps lowest col
      }
#pragma unroll
      for (int off = 1; off < 16; off <<= 1) {
        float ov = __shfl_xor(bv, off, 64);
        int oc = __shfl_xor(bc, off, 64);
        if (ov < bv || (ov == bv && oc < bc)) { bv = ov; bc = oc; }
      }
      if (tx == 0) { sV[wc * 256 + rloc] = bv; sI[wc * 256 + rloc] = bc; }
    }
  }
  __syncthreads();
  if (t < 256) {
    float v0 = sV[t], v1 = sV[256 + t];
    int i0 = sI[t], i1 = sI[256 + t];
    int take1 = (v1 < v0) || (v1 == v0 && i1 < i0);
    pVal[(size_t)nt * N_ROWS + m0 + t] = take1 ? v1 : v0;
    pIdx[(size_t)nt * N_ROWS + m0 + t] = take1 ? i1 : i0;
  }
}

// ---------- fused post (R11 structure; NPART 128 -> 64) ----------
__global__ __launch_bounds__(256) void k_post(const float* __restrict__ pVal,
                                              const int* __restrict__ pIdx,
                                              const float* __restrict__ z,
                                              const float* __restrict__ E,
                                              float* __restrict__ out,
                                              float* __restrict__ out_loss,
                                              float* __restrict__ out_idx) {
  __shared__ float sV[8][32];
  __shared__ int   sI[8][32];
  __shared__ int   fI[32];
  const int t = threadIdx.x;
  const int r = t & 31, s = t >> 5;
  const int n0 = blockIdx.x * 32;
  const int n = n0 + r;

  float mv = 3.4e38f;
  int mi = 0x7fffffff;
#pragma unroll
  for (int i = 0; i < 8; ++i) {
    int s2 = s * 8 + i;
    float v = pVal[(size_t)s2 * N_ROWS + n];
    int id = pIdx[(size_t)s2 * N_ROWS + n];
    if (v < mv || (v == mv && id < mi)) { mv = v; mi = id; }
  }
  sV[s][r] = mv;
  sI[s][r] = mi;
  __syncthreads();
  if (t < 32) {
    float bv = sV[0][t];
    int bc = sI[0][t];
#pragma unroll
    for (int s3 = 1; s3 < 8; ++s3) {
      float v = sV[s3][t];
      int id = sI[s3][t];
      if (v < bv || (v == bv && id < bc)) { bv = v; bc = id; }
    }
    fI[t] = bc;
    out_idx[n0 + t] = (float)bc;
  }
  __syncthreads();

  const int idx = fI[r];
  const int b = n >> 10, hw = n & 1023;
  const float4* erow4 = (const float4*)(E + (size_t)idx * E_DIM + s * 32);
  const float* zrow = z + ((size_t)b * E_DIM + s * 32) * HW + hw;
  float* orow = out + ((size_t)b * E_DIM + s * 32) * HW + hw;
  float acc = 0.f;
#pragma unroll
  for (int c4 = 0; c4 < 8; ++c4) {
    float4 e4 = erow4[c4];
    float ev[4] = {e4.x, e4.y, e4.z, e4.w};
#pragma unroll
    for (int j2 = 0; j2 < 4; ++j2) {
      int c = c4 * 4 + j2;
      float zv = zrow[(size_t)c * HW];
      orow[(size_t)c * HW] = ev[j2];
      float d = ev[j2] - zv;
      acc = fmaf(d, d, acc);
    }
  }
  for (int off = 32; off > 0; off >>= 1) acc += __shfl_down(acc, off, 64);
  __shared__ float wsum[4];
  if ((t & 63) == 0) wsum[t >> 6] = acc;
  __syncthreads();
  if (t == 0)
    atomicAdd(out_loss, ((wsum[0] + wsum[1]) + (wsum[2] + wsum[3])) * (1.25f / 2097152.f));
}

extern "C" void kernel_launch(void* const* d_in, const int* in_sizes, int n_in,
                              void* d_out, int out_size, void* d_ws, size_t ws_size,
                              hipStream_t stream) {
  const float* z = (const float*)d_in[0];
  const float* E = (const float*)d_in[1];
  float* out = (float*)d_out;
  float* out_loss = out + 2097152;  // after z_q (8*256*32*32)
  float* out_idx = out + 2097153;

  // workspace (~28 MB): Ah|Al f16[8][8192][32], Bh|Bl f16[8][16384][32],
  //                     eNorm, zNorm, pVal[64][8192], pIdx[64][8192]
  _Float16* Ah = (_Float16*)d_ws;
  _Float16* Al = Ah + (size_t)N_ROWS * E_DIM;
  _Float16* Bh = Al + (size_t)N_ROWS * E_DIM;
  _Float16* Bl = Bh + (size_t)N_E * E_DIM;
  float* eNorm = (float*)(Bl + (size_t)N_E * E_DIM);
  float* zNorm = eNorm + N_E;
  float* pVal = zNorm + N_ROWS;
  int* pIdx = (int*)(pVal + (size_t)NPART * N_ROWS);

  k_prep<<<ZB_Z + EB_E, 256, 0, stream>>>(
      z, E, Ah, Al, Bh, Bl, eNorm, zNorm, out_loss);
  k_scores_mfma<<<dim3(N_ROWS / 256, N_E / 256), 512, 0, stream>>>(
      Ah, Al, Bh, Bl, eNorm, zNorm, pVal, pIdx);
  k_post<<<N_ROWS / 32, 256, 0, stream>>>(pVal, pIdx, z, E, out, out_loss, out_idx);
}

// Round 3
// 302.314 us; speedup vs baseline: 1.0335x; 1.0335x over previous
//
#include <hip/hip_runtime.h>

#define E_DIM  256
#define N_E    16384
#define N_ROWS 8192
#define HW     1024
#define NPART  64           // n-tiles of 256 cols

typedef _Float16 f16x8 __attribute__((ext_vector_type(8)));
typedef float    f32x4 __attribute__((ext_vector_type(4)));

#define ESCALE   1048576.0f          // 2^20 (exact)
#define UNSCALE  1.9073486328125e-6f // 2^-19: acc*2^-19 == 2*dot

// async 16B global->LDS copy: HW writes lds_base + lane*16 (wave-uniform base)
__device__ __forceinline__ void gld_lds16(_Float16* lds, const _Float16* g) {
  __builtin_amdgcn_global_load_lds(
      (__attribute__((address_space(1))) void*)(g),
      (__attribute__((address_space(3))) void*)(lds), 16, 0, 0);
}

// ---------- fused prep (verbatim R11, passed) ----------
#define ZB_Z    256
#define EB_E    512
__global__ __launch_bounds__(256) void k_prep(const float* __restrict__ z,
                                              const float* __restrict__ E,
                                              _Float16* __restrict__ Ah,
                                              _Float16* __restrict__ Al,
                                              _Float16* __restrict__ Bh,
                                              _Float16* __restrict__ Bl,
                                              float* __restrict__ eNorm,
                                              float* __restrict__ zNorm,
                                              float* __restrict__ out_loss) {
#pragma clang fp contract(off)
  const int bi = blockIdx.x, t = threadIdx.x;

  if (bi < ZB_Z) {
    // ---- z section: 32-row tile ----
    __shared__ float sLZ[256][32];   // 32 KB z tile [channel][row]
    __shared__ float sN2[16][32];    // chain partials [c16][row]
    const int n0 = bi * 32;
    const int b = n0 >> 10, hw0 = n0 & 1023;

    {
      const int nl = t & 31, cs = t >> 5;
      const float* zb = z + (size_t)b * E_DIM * HW + hw0 + nl;
#pragma unroll 4
      for (int it = 0; it < 32; ++it) {
        int c = it * 8 + cs;
        sLZ[c][nl] = zb[(size_t)c * HW];
      }
    }
    __syncthreads();

    // phase L: limbs. thread = (row nl, segment seg = kc)
    {
      const int nl = t & 31, seg = t >> 5;
      const int n = n0 + nl;
      const int perm = (n >> 1) & 3;
#pragma unroll
      for (int u = 0; u < 4; ++u) {
        const int c0 = seg * 32 + u * 8;
        f16x8 hh, ll;
#pragma unroll
        for (int j = 0; j < 8; ++j) {
          float v = sLZ[c0 + j][nl];
          _Float16 hi = (_Float16)v;
          hh[j] = hi;
          ll[j] = (_Float16)(v - (float)hi);
        }
        size_t dst = (size_t)seg * (N_ROWS * 32) + (size_t)n * 32 + (size_t)(u ^ perm) * 8;
        *(f16x8*)&Ah[dst] = hh;
        *(f16x8*)&Al[dst] = ll;
      }
    }

    // phase N: numpy-exact chains
#pragma unroll
    for (int it = 0; it < 2; ++it) {
      int task = it * 256 + t;
      int nl = task & 31, c16 = task >> 5;
      int h = c16 >> 3, j = c16 & 7;
      float r = 0.f;
#pragma unroll
      for (int i = 0; i < 16; ++i) {
        float v = sLZ[h * 128 + i * 8 + j][nl];
        r = r + v * v;
      }
      sN2[c16][nl] = r;
    }
    __syncthreads();
    if (t < 32) {
      float q[16];
#pragma unroll
      for (int c16 = 0; c16 < 16; ++c16) q[c16] = sN2[c16][t];
      float h0 = ((q[0] + q[1]) + (q[2] + q[3])) + ((q[4] + q[5]) + (q[6] + q[7]));
      float h1 = ((q[8] + q[9]) + (q[10] + q[11])) + ((q[12] + q[13]) + (q[14] + q[15]));
      zNorm[n0 + t] = h0 + h1;
    }
  } else {
    // ---- E section ----
    __shared__ float sNP[8][32];
    const int be = bi - ZB_Z;
    if (be == 0 && t == 0) out_loss[0] = 0.f;
    const int kc = t >> 5, rl = t & 31;
    const int k = be * 32 + rl;
    const int perm = (k >> 1) & 3;
    const float* src = E + (size_t)k * E_DIM + kc * 32;

    float4 v4[8];
#pragma unroll
    for (int u2 = 0; u2 < 8; ++u2) v4[u2] = ((const float4*)src)[u2];

    float nsum = 0.f;
    size_t base = (size_t)kc * (N_E * 32) + (size_t)k * 32;
#pragma unroll
    for (int u = 0; u < 4; ++u) {
      float v[8] = {v4[u * 2].x, v4[u * 2].y, v4[u * 2].z, v4[u * 2].w,
                    v4[u * 2 + 1].x, v4[u * 2 + 1].y, v4[u * 2 + 1].z, v4[u * 2 + 1].w};
      f16x8 hh, ll;
#pragma unroll
      for (int j = 0; j < 8; ++j) {
        nsum = nsum + v[j] * v[j];
        float s = v[j] * ESCALE;
        _Float16 hi = (_Float16)s;
        hh[j] = hi;
        ll[j] = (_Float16)(s - (float)hi);
      }
      *(f16x8*)&Bh[base + (size_t)(u ^ perm) * 8] = hh;
      *(f16x8*)&Bl[base + (size_t)(u ^ perm) * 8] = ll;
    }
    sNP[kc][rl] = nsum;
    __syncthreads();
    if (t < 32) {
      float s = 0.f;
#pragma unroll
      for (int kc2 = 0; kc2 < 8; ++kc2) s += sNP[kc2][t];
      eNorm[be * 32 + t] = s;
    }
  }
}

// ---------- main: fp16-limb MFMA GEMM. R15: faithful 8-phase template port.
// Per kc: opening {vmcnt(0); s_barrier} (drains staging issued >=4 phases ago),
// then 8 phases, phase j = { ds_read bh/bl[j] (+A frags in phase 0) |
// stage 2 gld_lds (phases 0-3 only) | sched_barrier | s_barrier | lgkmcnt(0) |
// setprio(1) 12 MFMA setprio(0) | s_barrier }. Per-phase LDS dump is 16 b128/CU
// (~190 cyc) vs 466 cyc MFMA -> drain windows small + adjacent to consumers.
// Numerics (limb order hh,hl,lh, acc mapping, swizzle, tie-breaks) identical.
__global__ __launch_bounds__(512, 2) void k_scores_mfma(
    const _Float16* __restrict__ Ah, const _Float16* __restrict__ Al,
    const _Float16* __restrict__ Bh, const _Float16* __restrict__ Bl,
    const float* __restrict__ eNorm, const float* __restrict__ zNorm,
    float* __restrict__ pVal, int* __restrict__ pIdx) {
#pragma clang fp contract(off)
  __shared__ alignas(16) _Float16 L[2][2][2][256][32];  // 128 KiB

  const int mt = blockIdx.x, nt = blockIdx.y;
  const int m0 = mt * 256, n0 = nt * 256;

  const int t = threadIdx.x;
  const int lane = t & 63, w = t >> 6;
  const int tx = lane & 15, quad = lane >> 4;
  const int wr = w & 3, wc = w >> 2;          // wave grid 4 (m) x 2 (n)
  const int wm = wr * 64, wn = wc * 128;      // per-wave output 64 x 128
  const int swz = (quad ^ ((tx >> 1) & 3)) * 8;  // physical f16 offset of logical block

  // staging role: wave w stages array (w>>1 in {Ah,Al,Bh,Bl}), half (w&1)
  const int arr = w >> 1, hf = w & 1;
  const _Float16* gstage;
  size_t plane;
  _Float16* lstage0;
  if (arr == 0)      { gstage = Ah + (size_t)(m0 + hf * 128) * 32; plane = (size_t)N_ROWS * 32; lstage0 = &L[0][0][0][hf * 128][0]; }
  else if (arr == 1) { gstage = Al + (size_t)(m0 + hf * 128) * 32; plane = (size_t)N_ROWS * 32; lstage0 = &L[0][0][1][hf * 128][0]; }
  else if (arr == 2) { gstage = Bh + (size_t)(n0 + hf * 128) * 32; plane = (size_t)N_E * 32;    lstage0 = &L[0][1][0][hf * 128][0]; }
  else               { gstage = Bl + (size_t)(n0 + hf * 128) * 32; plane = (size_t)N_E * 32;    lstage0 = &L[0][1][1][hf * 128][0]; }
  gstage += lane * 8;

  f32x4 acc[4][8];
#pragma unroll
  for (int i = 0; i < 4; ++i)
#pragma unroll
    for (int j = 0; j < 8; ++j) acc[i][j] = (f32x4){0.f, 0.f, 0.f, 0.f};

  // prologue: stage kc=0 into buf 0 (8 x 1KB per wave); drained at kc=0 opening
  {
#pragma unroll
    for (int c = 0; c < 8; ++c) gld_lds16(lstage0 + c * 512, gstage + c * 512);
  }

#pragma unroll 2
  for (int kc = 0; kc < 8; ++kc) {
    const int buf = kc & 1;
    const _Float16* Ab = &L[buf][0][0][0][0];
    const _Float16* Bb = &L[buf][1][0][0][0];
    _Float16* lpre = lstage0 + (size_t)(buf ^ 1) * 32768;   // other buffer
    const _Float16* gpre = gstage + (size_t)(kc + 1) * plane;
    const bool pf = (kc < 7);

    // ---- kc opening: my staging loads for buf landed; sync all waves
    asm volatile("s_waitcnt vmcnt(0)" ::: "memory");
    __builtin_amdgcn_s_barrier();

    f16x8 ah[4], al[4];

#pragma unroll
    for (int j = 0; j < 8; ++j) {
      // phase j reads: one B column pair (+ all A frags in phase 0)
      f16x8 bh = *(const f16x8*)&Bb[(wn + j * 16 + tx) * 32 + swz];
      f16x8 bl = *(const f16x8*)&Bb[(wn + j * 16 + tx) * 32 + 8192 + swz];
      if (j == 0) {
#pragma unroll
        for (int i = 0; i < 4; ++i) {
          const int ro = (wm + i * 16 + tx) * 32 + swz;
          ah[i] = *(const f16x8*)&Ab[ro];
          al[i] = *(const f16x8*)&Ab[ro + 8192];
        }
      }
      // staging spread over phases 0-3: 2 gld_lds each -> >=4 phases of cover
      if (pf && j < 4) {
        gld_lds16(lpre + (size_t)(2 * j) * 512, gpre + (size_t)(2 * j) * 512);
        gld_lds16(lpre + (size_t)(2 * j + 1) * 512, gpre + (size_t)(2 * j + 1) * 512);
      }
      __builtin_amdgcn_sched_barrier(0);   // pin reads+stage above the barrier
      __builtin_amdgcn_s_barrier();
      asm volatile("s_waitcnt lgkmcnt(0)" ::: "memory");
      __builtin_amdgcn_sched_barrier(0);
      __builtin_amdgcn_s_setprio(1);
#pragma unroll
      for (int i = 0; i < 4; ++i) {
        acc[i][j] = __builtin_amdgcn_mfma_f32_16x16x32_f16(ah[i], bh, acc[i][j], 0, 0, 0);
        acc[i][j] = __builtin_amdgcn_mfma_f32_16x16x32_f16(ah[i], bl, acc[i][j], 0, 0, 0);
        acc[i][j] = __builtin_amdgcn_mfma_f32_16x16x32_f16(al[i], bh, acc[i][j], 0, 0, 0);
      }
      __builtin_amdgcn_s_setprio(0);
      __builtin_amdgcn_sched_barrier(0);
      __builtin_amdgcn_s_barrier();
    }
  }

  // ---- epilogue: score + argmin (first-index tie-break) ----
  float* sF  = (float*)&L[0][0][0][0][0];
  float* zNl = sF;                  // [256]
  float* eNl = sF + 256;            // [256]
  float* sV  = sF + 512;            // [2][256]
  int*   sI  = (int*)(sF + 1024);   // [2][256]
  if (t < 256) zNl[t] = zNorm[m0 + t];
  else         eNl[t - 256] = eNorm[n0 + t - 256];
  __syncthreads();

#pragma unroll
  for (int i = 0; i < 4; ++i) {
#pragma unroll
    for (int r = 0; r < 4; ++r) {
      const int rloc = wm + i * 16 + quad * 4 + r;
      const float zn = zNl[rloc];
      float bv = 3.4e38f;
      int bc = 0x7fffffff;
#pragma unroll
      for (int jj = 0; jj < 8; ++jj) {
        const int col = wn + jj * 16 + tx;
        float s = (zn + eNl[col]) - acc[i][jj][r] * UNSCALE;
        if (s < bv) { bv = s; bc = n0 + col; }   // jj ascending: strict < keeps lowest col
      }
#pragma unroll
      for (int off = 1; off < 16; off <<= 1) {
        float ov = __shfl_xor(bv, off, 64);
        int oc = __shfl_xor(bc, off, 64);
        if (ov < bv || (ov == bv && oc < bc)) { bv = ov; bc = oc; }
      }
      if (tx == 0) { sV[wc * 256 + rloc] = bv; sI[wc * 256 + rloc] = bc; }
    }
  }
  __syncthreads();
  if (t < 256) {
    float v0 = sV[t], v1 = sV[256 + t];
    int i0 = sI[t], i1 = sI[256 + t];
    int take1 = (v1 < v0) || (v1 == v0 && i1 < i0);
    pVal[(size_t)nt * N_ROWS + m0 + t] = take1 ? v1 : v0;
    pIdx[(size_t)nt * N_ROWS + m0 + t] = take1 ? i1 : i0;
  }
}

// ---------- fused post (R11 structure; NPART 128 -> 64) ----------
__global__ __launch_bounds__(256) void k_post(const float* __restrict__ pVal,
                                              const int* __restrict__ pIdx,
                                              const float* __restrict__ z,
                                              const float* __restrict__ E,
                                              float* __restrict__ out,
                                              float* __restrict__ out_loss,
                                              float* __restrict__ out_idx) {
  __shared__ float sV[8][32];
  __shared__ int   sI[8][32];
  __shared__ int   fI[32];
  const int t = threadIdx.x;
  const int r = t & 31, s = t >> 5;
  const int n0 = blockIdx.x * 32;
  const int n = n0 + r;

  float mv = 3.4e38f;
  int mi = 0x7fffffff;
#pragma unroll
  for (int i = 0; i < 8; ++i) {
    int s2 = s * 8 + i;
    float v = pVal[(size_t)s2 * N_ROWS + n];
    int id = pIdx[(size_t)s2 * N_ROWS + n];
    if (v < mv || (v == mv && id < mi)) { mv = v; mi = id; }
  }
  sV[s][r] = mv;
  sI[s][r] = mi;
  __syncthreads();
  if (t < 32) {
    float bv = sV[0][t];
    int bc = sI[0][t];
#pragma unroll
    for (int s3 = 1; s3 < 8; ++s3) {
      float v = sV[s3][t];
      int id = sI[s3][t];
      if (v < bv || (v == bv && id < bc)) { bv = v; bc = id; }
    }
    fI[t] = bc;
    out_idx[n0 + t] = (float)bc;
  }
  __syncthreads();

  const int idx = fI[r];
  const int b = n >> 10, hw = n & 1023;
  const float4* erow4 = (const float4*)(E + (size_t)idx * E_DIM + s * 32);
  const float* zrow = z + ((size_t)b * E_DIM + s * 32) * HW + hw;
  float* orow = out + ((size_t)b * E_DIM + s * 32) * HW + hw;
  float acc = 0.f;
#pragma unroll
  for (int c4 = 0; c4 < 8; ++c4) {
    float4 e4 = erow4[c4];
    float ev[4] = {e4.x, e4.y, e4.z, e4.w};
#pragma unroll
    for (int j2 = 0; j2 < 4; ++j2) {
      int c = c4 * 4 + j2;
      float zv = zrow[(size_t)c * HW];
      orow[(size_t)c * HW] = ev[j2];
      float d = ev[j2] - zv;
      acc = fmaf(d, d, acc);
    }
  }
  for (int off = 32; off > 0; off >>= 1) acc += __shfl_down(acc, off, 64);
  __shared__ float wsum[4];
  if ((t & 63) == 0) wsum[t >> 6] = acc;
  __syncthreads();
  if (t == 0)
    atomicAdd(out_loss, ((wsum[0] + wsum[1]) + (wsum[2] + wsum[3])) * (1.25f / 2097152.f));
}

extern "C" void kernel_launch(void* const* d_in, const int* in_sizes, int n_in,
                              void* d_out, int out_size, void* d_ws, size_t ws_size,
                              hipStream_t stream) {
  const float* z = (const float*)d_in[0];
  const float* E = (const float*)d_in[1];
  float* out = (float*)d_out;
  float* out_loss = out + 2097152;  // after z_q (8*256*32*32)
  float* out_idx = out + 2097153;

  // workspace (~28 MB): Ah|Al f16[8][8192][32], Bh|Bl f16[8][16384][32],
  //                     eNorm, zNorm, pVal[64][8192], pIdx[64][8192]
  _Float16* Ah = (_Float16*)d_ws;
  _Float16* Al = Ah + (size_t)N_ROWS * E_DIM;
  _Float16* Bh = Al + (size_t)N_ROWS * E_DIM;
  _Float16* Bl = Bh + (size_t)N_E * E_DIM;
  float* eNorm = (float*)(Bl + (size_t)N_E * E_DIM);
  float* zNorm = eNorm + N_E;
  float* pVal = zNorm + N_ROWS;
  int* pIdx = (int*)(pVal + (size_t)NPART * N_ROWS);

  k_prep<<<ZB_Z + EB_E, 256, 0, stream>>>(
      z, E, Ah, Al, Bh, Bl, eNorm, zNorm, out_loss);
  k_scores_mfma<<<dim3(N_ROWS / 256, N_E / 256), 512, 0, stream>>>(
      Ah, Al, Bh, Bl, eNorm, zNorm, pVal, pIdx);
  k_post<<<N_ROWS / 32, 256, 0, stream>>>(pVal, pIdx, z, E, out, out_loss, out_idx);
}